// Round 1
// baseline (123.307 us; speedup 1.0000x reference)
//
#include <hip/hip_runtime.h>
#include <hip/hip_fp16.h>
#include <math.h>

// ---------------------------------------------------------------------------
// 2-layer GCN on MI355X. N=50000 (<2^16), E=800000, C: 64 -> 64 -> 40.
// hs1[i] = (x@W1)[i]           (fp16, UNSCALED so gemm1 can run before dinv);
// h1b[d] = relu((hs1[d]*dinv[d] + sum_e hs1[src]*dinv[src]) * dinv[d] + b1);
// hs2[i] = (h1b@W2)[i]*dinv[i] (fp16);
// out[d] = log_softmax((hs2[d] + sum_e hs2[src]) * dinv[d] + b2).
//
// 5 dispatches (was 6 — gather_relu and gemm2 fused, h1b never hits global):
//   k_init:      bcur[b] = b*SLACK.
//   k_part_gemm: blocks [0,npart) partition edges into slack dst-buckets
//                (LDS histogram -> one global atomic per bucket -> scatter
//                packed (local9|src16)); blocks [npart,..) run the LDS-tiled
//                x@W1 GEMM concurrently (data-independent).
//   k_build:     one wg per bucket: LDS degree count -> 512-wide LDS scan ->
//                row_beg/row_end/dinv -> bucket-local ushort CSR fill.
//   k_gather_gemm2: 512 thr / 64 rows. Each of 8 waves gathers 8 rows
//                (8 edges x 8 lanes x uint4, 3 shfl_xor butterflies, fused
//                dinv[src]+bias+relu) and writes f32 results straight into
//                the transposed LDS GEMM tile; then h1b_tile@W2 with
//                dinv-scaled fp16 out. h1b global buffer eliminated.
//   k_gather_lsm40: wave/dst-row; 4 edges x 16 lanes x 8B; fused bias +
//                log_softmax -> fp32.
// Lessons: random small global stores amplify ~10-16x unless bucket-local
// (r3-5); per-lane weight arrays spill to scratch (r6); traffic cuts alone
// were null (r9) -> dispatch serialization + latency are the remaining cost,
// hence this round's dispatch fusion.
// ---------------------------------------------------------------------------

#define SHIFT   9
#define RPB     512
#define NBMAX   128
#define SLACK   16384
#define CHUNK_P 2048

__global__ void k_init(int* __restrict__ bcur, int nb) {
    int t = threadIdx.x;
    if (t < nb) bcur[t] = t * SLACK;
}

// --- fused: edge partition (blocks < npart) || x@W1 GEMM (rest) -------------
__global__ void k_part_gemm(const long long* __restrict__ ei64,
                            const int* __restrict__ ei32,
                            int* __restrict__ bcur,
                            unsigned int* __restrict__ ebkt, int E, int nb,
                            int npart,
                            const float* __restrict__ x,
                            const float* __restrict__ W1,
                            __half* __restrict__ hs1, int n) {
    __shared__ __align__(16) float smem[2 * 64 * 68];
    if ((int)blockIdx.x < npart) {
        // ---------------- partition branch ----------------
        int* cnt   = (int*)smem;
        int* rbase = cnt + NBMAX;
        int* is64p = rbase + NBMAX;
        int t = threadIdx.x;
        if (t < NBMAX) cnt[t] = 0;
        if (t == 0) {
            int is64 = 1;
            for (int i = 0; i < 64; ++i)
                if (ei32[2 * i + 1] != 0) { is64 = 0; break; }
            *is64p = is64;
        }
        __syncthreads();
        int is64 = *is64p;
        int lo = blockIdx.x * CHUNK_P;
        int hi = lo + CHUNK_P; if (hi > E) hi = E;
        for (int e = lo + t; e < hi; e += 256) {
            int d = is64 ? (int)ei64[E + e] : ei32[E + e];
            atomicAdd(&cnt[d >> SHIFT], 1);
        }
        __syncthreads();
        for (int b = t; b < nb; b += 256) {
            int c = cnt[b];
            rbase[b] = c ? atomicAdd(&bcur[b], c) : 0;
            cnt[b] = 0;
        }
        __syncthreads();
        for (int e = lo + t; e < hi; e += 256) {
            int s, d;
            if (is64) { s = (int)ei64[e]; d = (int)ei64[E + e]; }
            else      { s = ei32[e];      d = ei32[E + e]; }
            int b = d >> SHIFT;
            int pos = rbase[b] + atomicAdd(&cnt[b], 1);
            ebkt[pos] = ((unsigned int)(d & (RPB - 1)) << 16) | (unsigned int)s;
        }
    } else {
        // ---------------- GEMM branch (x@W1, unscaled fp16 out) -------------
        float* Wl = smem;
        float* Xl = smem + 64 * 68;
        int t  = threadIdx.x;
        int tr = t >> 4, tc = t & 15;
        int base = (blockIdx.x - npart) * 64;

        for (int i = t; i < 64 * 17; i += 256) {
            int k = i / 17, c4 = (i % 17) * 4;
            float4 w = make_float4(0.f, 0.f, 0.f, 0.f);
            if (c4 < 64) w = *(const float4*)&W1[k * 64 + c4];
            *(float4*)&Wl[k * 68 + c4] = w;
        }
        for (int rr = tr; rr < 64; rr += 16) {
            int row = base + rr; if (row >= n) row = n - 1;
            float4 v = *(const float4*)&x[(size_t)row * 64 + tc * 4];
            Xl[(tc * 4 + 0) * 68 + rr] = v.x;
            Xl[(tc * 4 + 1) * 68 + rr] = v.y;
            Xl[(tc * 4 + 2) * 68 + rr] = v.z;
            Xl[(tc * 4 + 3) * 68 + rr] = v.w;
        }
        __syncthreads();

        float acc[4][4] = {{0.f}};
#pragma unroll 8
        for (int k = 0; k < 64; ++k) {
            float4 xv = *(const float4*)&Xl[k * 68 + tr * 4];
            float4 wv = *(const float4*)&Wl[k * 68 + tc * 4];
            acc[0][0] = fmaf(xv.x, wv.x, acc[0][0]);
            acc[0][1] = fmaf(xv.x, wv.y, acc[0][1]);
            acc[0][2] = fmaf(xv.x, wv.z, acc[0][2]);
            acc[0][3] = fmaf(xv.x, wv.w, acc[0][3]);
            acc[1][0] = fmaf(xv.y, wv.x, acc[1][0]);
            acc[1][1] = fmaf(xv.y, wv.y, acc[1][1]);
            acc[1][2] = fmaf(xv.y, wv.z, acc[1][2]);
            acc[1][3] = fmaf(xv.y, wv.w, acc[1][3]);
            acc[2][0] = fmaf(xv.z, wv.x, acc[2][0]);
            acc[2][1] = fmaf(xv.z, wv.y, acc[2][1]);
            acc[2][2] = fmaf(xv.z, wv.z, acc[2][2]);
            acc[2][3] = fmaf(xv.z, wv.w, acc[2][3]);
            acc[3][0] = fmaf(xv.w, wv.x, acc[3][0]);
            acc[3][1] = fmaf(xv.w, wv.y, acc[3][1]);
            acc[3][2] = fmaf(xv.w, wv.z, acc[3][2]);
            acc[3][3] = fmaf(xv.w, wv.w, acc[3][3]);
        }
#pragma unroll
        for (int i = 0; i < 4; ++i) {
            int r = base + tr * 4 + i;
            if (r >= n) break;
            __half2 p0 = __floats2half2_rn(acc[i][0], acc[i][1]);
            __half2 p1 = __floats2half2_rn(acc[i][2], acc[i][3]);
            *(__half2*)&hs1[(size_t)r * 64 + tc * 4]     = p0;
            *(__half2*)&hs1[(size_t)r * 64 + tc * 4 + 2] = p1;
        }
    }
}

// --- per-bucket: degree, scan, row_beg/row_end/dinv, ushort CSR fill --------
__global__ void k_build(const unsigned int* __restrict__ ebkt,
                        const int* __restrict__ bcur,
                        int* __restrict__ row_beg, int* __restrict__ row_end,
                        float* __restrict__ dinv,
                        unsigned short* __restrict__ csr_src, int N) {
    __shared__ int cnt[RPB];
    __shared__ int wsum[256];
    int t = threadIdx.x, b = blockIdx.x;
    int rows0 = b << SHIFT;
    int nrows = N - rows0; if (nrows > RPB) nrows = RPB;
    for (int i = t; i < RPB; i += 256) cnt[i] = 0;
    __syncthreads();
    int lo = b * SLACK, hi = bcur[b];
    for (int e = lo + t; e < hi; e += 256)
        atomicAdd(&cnt[ebkt[e] >> 16], 1);
    __syncthreads();
    int i0 = 2 * t, i1 = 2 * t + 1;
    int c0 = cnt[i0], c1 = cnt[i1];
    wsum[t] = c0 + c1;
    __syncthreads();
    for (int off = 1; off < 256; off <<= 1) {
        int u = (t >= off) ? wsum[t - off] : 0;
        __syncthreads();
        wsum[t] += u;
        __syncthreads();
    }
    int beg0 = lo + ((t == 0) ? 0 : wsum[t - 1]);
    int beg1 = beg0 + c0;
    cnt[i0] = beg0;
    cnt[i1] = beg1;
    if (i0 < nrows) {
        row_beg[rows0 + i0] = beg0; row_end[rows0 + i0] = beg0 + c0;
        dinv[rows0 + i0] = rsqrtf((float)c0 + 1.0f);
    }
    if (i1 < nrows) {
        row_beg[rows0 + i1] = beg1; row_end[rows0 + i1] = beg1 + c1;
        dinv[rows0 + i1] = rsqrtf((float)c1 + 1.0f);
    }
    __syncthreads();
    for (int e = lo + t; e < hi; e += 256) {
        unsigned int v = ebkt[e];
        int pos = atomicAdd(&cnt[v >> 16], 1);
        csr_src[pos] = (unsigned short)(v & 0xffffu);
    }
}

// --- FUSED: gather C=64 + dinv[src]+bias+relu -> LDS tile -> @W2*dinv -------
// 512 threads, 64 rows/block. 8 waves x 8 rows each; gather identical to the
// old k_gather_relu64 but the f32 relu output goes straight into the
// transposed GEMM tile Xl[channel][row]. Then the layer-2 GEMM runs from LDS.
// h1b never exists in global memory.
__global__ __launch_bounds__(512, 4)
void k_gather_gemm2(const __half* __restrict__ hs,      // hs1 [N][64] fp16
                    const float* __restrict__ W,        // W2  [64][40] f32
                    const int* __restrict__ rbg,
                    const int* __restrict__ ren,
                    const unsigned short* __restrict__ ci,
                    const float* __restrict__ dinv,
                    const float* __restrict__ bias,     // b1
                    __half* __restrict__ hs2,           // [N][40] fp16 out
                    int n) {
    __shared__ float Xl[64 * 68];   // [ch][row] f32 h1b tile (stride 68)
    __shared__ float Wl[64 * 44];   // W2 padded to stride 44
    int t = threadIdx.x;
    int base = blockIdx.x * 64;

    // stage W2 (64x40 -> 64x44, zero pad)
    for (int i = t; i < 64 * 11; i += 512) {
        int k = i / 11, c4 = (i % 11) * 4;
        float4 w = make_float4(0.f, 0.f, 0.f, 0.f);
        if (c4 < 40) w = *(const float4*)&W[k * 40 + c4];
        *(float4*)&Wl[k * 44 + c4] = w;
    }

    int w    = t >> 6;        // wave 0..7
    int lane = t & 63;
    int g = lane >> 3, q = lane & 7;

    for (int it = 0; it < 8; ++it) {
        int row = base + w * 8 + it;
        if (row >= n) break;
        int beg = rbg[row], end = ren[row];

        float4 aa = make_float4(0.f, 0.f, 0.f, 0.f);
        float4 ab = make_float4(0.f, 0.f, 0.f, 0.f);
        for (int eb = beg; eb < end; eb += 64) {
            int mm = end - eb; if (mm > 64) mm = 64;
            int idx = (lane < mm) ? (int)ci[eb + lane] : 0;
            for (int j = 0; 8 * j < mm; ++j) {
                int e = 8 * j + g;
                int s = __shfl(idx, e, 64);
                if (eb + e < end) {
                    float ds = dinv[s];
                    uint4 u = ((const uint4*)(hs + ((size_t)s << 6)))[q];
                    float2 f0 = __half22float2(*(__half2*)&u.x);
                    float2 f1 = __half22float2(*(__half2*)&u.y);
                    float2 f2 = __half22float2(*(__half2*)&u.z);
                    float2 f3 = __half22float2(*(__half2*)&u.w);
                    aa.x = fmaf(f0.x, ds, aa.x); aa.y = fmaf(f0.y, ds, aa.y);
                    aa.z = fmaf(f1.x, ds, aa.z); aa.w = fmaf(f1.y, ds, aa.w);
                    ab.x = fmaf(f2.x, ds, ab.x); ab.y = fmaf(f2.y, ds, ab.y);
                    ab.z = fmaf(f3.x, ds, ab.z); ab.w = fmaf(f3.y, ds, ab.w);
                }
            }
        }
#pragma unroll
        for (int o = 8; o < 64; o <<= 1) {
            aa.x += __shfl_xor(aa.x, o, 64); aa.y += __shfl_xor(aa.y, o, 64);
            aa.z += __shfl_xor(aa.z, o, 64); aa.w += __shfl_xor(aa.w, o, 64);
            ab.x += __shfl_xor(ab.x, o, 64); ab.y += __shfl_xor(ab.y, o, 64);
            ab.z += __shfl_xor(ab.z, o, 64); ab.w += __shfl_xor(ab.w, o, 64);
        }
        // epilogue: every lane holds the 8 channel sums for octet q
        float dv = dinv[row];
        uint4 su = ((const uint4*)(hs + ((size_t)row << 6)))[q];
        float2 s0 = __half22float2(*(__half2*)&su.x);
        float2 s1 = __half22float2(*(__half2*)&su.y);
        float2 s2 = __half22float2(*(__half2*)&su.z);
        float2 s3 = __half22float2(*(__half2*)&su.w);
        float4 bv0 = *(const float4*)&bias[q * 8];
        float4 bv1 = *(const float4*)&bias[q * 8 + 4];
        float v0 = fmaxf((aa.x + s0.x * dv) * dv + bv0.x, 0.f);
        float v1 = fmaxf((aa.y + s0.y * dv) * dv + bv0.y, 0.f);
        float v2 = fmaxf((aa.z + s1.x * dv) * dv + bv0.z, 0.f);
        float v3 = fmaxf((aa.w + s1.y * dv) * dv + bv0.w, 0.f);
        float v4 = fmaxf((ab.x + s2.x * dv) * dv + bv1.x, 0.f);
        float v5 = fmaxf((ab.y + s2.y * dv) * dv + bv1.y, 0.f);
        float v6 = fmaxf((ab.z + s3.x * dv) * dv + bv1.z, 0.f);
        float v7 = fmaxf((ab.w + s3.y * dv) * dv + bv1.w, 0.f);
        // lane writes channel ch = q*8 + g of this row (64 lanes cover 64 ch)
        float s01 = (g & 1) ? v1 : v0;
        float s23 = (g & 1) ? v3 : v2;
        float s45 = (g & 1) ? v5 : v4;
        float s67 = (g & 1) ? v7 : v6;
        float s03 = (g & 2) ? s23 : s01;
        float s47 = (g & 2) ? s67 : s45;
        float val = (g & 4) ? s47 : s03;
        Xl[(q * 8 + g) * 68 + (row - base)] = val;
    }
    __syncthreads();

    // ---- layer-2 GEMM from LDS: out[r][c] = (Xl[:,r] . W2[:,c]) * dinv[r] --
    if (t < 256 && (t & 15) < 10) {
        int tr = t >> 4, tc = t & 15;
        float acc[4][4] = {{0.f}};
#pragma unroll 8
        for (int k = 0; k < 64; ++k) {
            float4 xv = *(const float4*)&Xl[k * 68 + tr * 4];
            float4 wv = *(const float4*)&Wl[k * 44 + tc * 4];
            acc[0][0] = fmaf(xv.x, wv.x, acc[0][0]);
            acc[0][1] = fmaf(xv.x, wv.y, acc[0][1]);
            acc[0][2] = fmaf(xv.x, wv.z, acc[0][2]);
            acc[0][3] = fmaf(xv.x, wv.w, acc[0][3]);
            acc[1][0] = fmaf(xv.y, wv.x, acc[1][0]);
            acc[1][1] = fmaf(xv.y, wv.y, acc[1][1]);
            acc[1][2] = fmaf(xv.y, wv.z, acc[1][2]);
            acc[1][3] = fmaf(xv.y, wv.w, acc[1][3]);
            acc[2][0] = fmaf(xv.z, wv.x, acc[2][0]);
            acc[2][1] = fmaf(xv.z, wv.y, acc[2][1]);
            acc[2][2] = fmaf(xv.z, wv.z, acc[2][2]);
            acc[2][3] = fmaf(xv.z, wv.w, acc[2][3]);
            acc[3][0] = fmaf(xv.w, wv.x, acc[3][0]);
            acc[3][1] = fmaf(xv.w, wv.y, acc[3][1]);
            acc[3][2] = fmaf(xv.w, wv.z, acc[3][2]);
            acc[3][3] = fmaf(xv.w, wv.w, acc[3][3]);
        }
#pragma unroll
        for (int i = 0; i < 4; ++i) {
            int r = base + tr * 4 + i;
            if (r >= n) break;
            float dvv = dinv[r];
            __half2 p0 = __floats2half2_rn(acc[i][0] * dvv, acc[i][1] * dvv);
            __half2 p1 = __floats2half2_rn(acc[i][2] * dvv, acc[i][3] * dvv);
            *(__half2*)&hs2[(size_t)r * 40 + tc * 4]     = p0;
            *(__half2*)&hs2[(size_t)r * 40 + tc * 4 + 2] = p1;
        }
    }
}

// --- Gather C=40 + bias + log_softmax -> fp32. 4 edges x 16 lanes x 8B. -----
__global__ void k_gather_lsm40(const __half* __restrict__ hs,
                               const int* __restrict__ rbg,
                               const int* __restrict__ ren,
                               const unsigned short* __restrict__ ci,
                               const float* __restrict__ dinv,
                               const float* __restrict__ bias,
                               float* __restrict__ out, int n) {
    int row = blockIdx.x * 4 + (threadIdx.x >> 6);
    if (row >= n) return;
    int lane = threadIdx.x & 63;
    int g = lane >> 4, q = lane & 15;
    int beg = rbg[row], end = ren[row];

    uint2 selfu = make_uint2(0u, 0u);
    if (q < 10)
        selfu = ((const uint2*)(hs + (size_t)row * 40))[q];

    float4 a = make_float4(0.f, 0.f, 0.f, 0.f);
    for (int base = beg; base < end; base += 64) {
        int mm = end - base; if (mm > 64) mm = 64;
        int idx = (lane < mm) ? (int)ci[base + lane] : 0;
        for (int j = 0; 4 * j < mm; ++j) {
            int s = __shfl(idx, 4 * j + g, 64);
            if (q < 10 && base + 4 * j + g < end) {
                uint2 u = ((const uint2*)(hs + (size_t)s * 40))[q];
                float2 f0 = __half22float2(*(__half2*)&u.x);
                float2 f1 = __half22float2(*(__half2*)&u.y);
                a.x += f0.x; a.y += f0.y; a.z += f1.x; a.w += f1.y;
            }
        }
    }
    a.x += __shfl_xor(a.x, 16, 64); a.y += __shfl_xor(a.y, 16, 64);
    a.z += __shfl_xor(a.z, 16, 64); a.w += __shfl_xor(a.w, 16, 64);
    a.x += __shfl_xor(a.x, 32, 64); a.y += __shfl_xor(a.y, 32, 64);
    a.z += __shfl_xor(a.z, 32, 64); a.w += __shfl_xor(a.w, 32, 64);

    float2 s0 = __half22float2(*(__half2*)&selfu.x);
    float2 s1 = __half22float2(*(__half2*)&selfu.y);
    float dv = dinv[row];
    float v0 = -INFINITY, v1 = -INFINITY, v2 = -INFINITY, v3 = -INFINITY;
    if (q < 10) {
        float4 bv = *(const float4*)&bias[q * 4];
        v0 = (a.x + s0.x) * dv + bv.x;
        v1 = (a.y + s0.y) * dv + bv.y;
        v2 = (a.z + s1.x) * dv + bv.z;
        v3 = (a.w + s1.y) * dv + bv.w;
    }
    float mx = fmaxf(fmaxf(v0, v1), fmaxf(v2, v3));
#pragma unroll
    for (int o = 1; o < 16; o <<= 1) mx = fmaxf(mx, __shfl_xor(mx, o, 64));
    float e0 = (q < 10) ? expf(v0 - mx) : 0.f;
    float e1 = (q < 10) ? expf(v1 - mx) : 0.f;
    float e2 = (q < 10) ? expf(v2 - mx) : 0.f;
    float e3 = (q < 10) ? expf(v3 - mx) : 0.f;
    float sm = (e0 + e1) + (e2 + e3);
#pragma unroll
    for (int o = 1; o < 16; o <<= 1) sm += __shfl_xor(sm, o, 64);
    if (lane < 16 && q < 10) {
        float ls = logf(sm);
        float4 r = make_float4(v0 - mx - ls, v1 - mx - ls,
                               v2 - mx - ls, v3 - mx - ls);
        *(float4*)&out[(size_t)row * 40 + q * 4] = r;
    }
}

extern "C" void kernel_launch(void* const* d_in, const int* in_sizes, int n_in,
                              void* d_out, int out_size, void* d_ws, size_t ws_size,
                              hipStream_t stream) {
    const float* x  = (const float*)d_in[0];
    const void*  ei = d_in[1];
    const float* W1 = (const float*)d_in[2];
    const float* b1 = (const float*)d_in[3];
    const float* W2 = (const float*)d_in[4];
    const float* b2 = (const float*)d_in[5];
    float* out = (float*)d_out;

    const int C_IN = 64;
    const int N = in_sizes[0] / C_IN;   // 50000
    const int E = in_sizes[1] / 2;      // 800000
    (void)n_in; (void)out_size; (void)ws_size;

    char* ws = (char*)d_ws;
    size_t off = 0;
    auto alloc = [&](size_t bytes) -> void* {
        void* p = ws + off;
        off += (bytes + 255) & ~(size_t)255;
        return p;
    };
    int*            bcur    = (int*)           alloc(NBMAX * 4);
    unsigned int*   ebkt    = (unsigned int*)  alloc((size_t)NBMAX * SLACK * 4);
    unsigned short* csr_src = (unsigned short*)alloc((size_t)NBMAX * SLACK * 2);
    int*            row_beg = (int*)           alloc((size_t)N * 4);
    int*            row_end = (int*)           alloc((size_t)N * 4);
    float*          dinv    = (float*)         alloc((size_t)N * 4);
    __half*         hs1     = (__half*)        alloc((size_t)N * 64 * 2);
    __half*         hs2     = (__half*)        alloc((size_t)N * 40 * 2);

    const int nb    = (N + RPB - 1) >> SHIFT;         // 98
    const int ngrid = (N + 63) / 64;                  // 782
    const int npart = (E + CHUNK_P - 1) / CHUNK_P;    // 391

    k_init<<<1, 128, 0, stream>>>(bcur, nb);
    k_part_gemm<<<npart + ngrid, 256, 0, stream>>>(
        (const long long*)ei, (const int*)ei, bcur, ebkt, E, nb, npart,
        x, W1, hs1, N);
    k_build<<<nb, 256, 0, stream>>>(ebkt, bcur, row_beg, row_end, dinv,
                                    csr_src, N);
    k_gather_gemm2<<<ngrid, 512, 0, stream>>>(
        hs1, W2, row_beg, row_end, csr_src, dinv, b1, hs2, N);
    k_gather_lsm40<<<(N + 3) / 4, 256, 0, stream>>>(
        hs2, row_beg, row_end, csr_src, dinv, b2, out, N);
}